// Round 8
// baseline (157.006 us; speedup 1.0000x reference)
//
#include <hip/hip_runtime.h>

#define DIN 1024
#define DC 64
#define KC 4096

typedef _Float16 f16x8 __attribute__((ext_vector_type(8)));
typedef _Float16 f16x4 __attribute__((ext_vector_type(4)));
typedef float f32x4 __attribute__((ext_vector_type(4)));

__device__ __forceinline__ void gll16(const void* g, void* l) {
    __builtin_amdgcn_global_load_lds(
        (const __attribute__((address_space(1))) unsigned int*)g,
        (__attribute__((address_space(3))) unsigned int*)l, 16, 0, 0);
}

// ---------------------------------------------------------------------------
// Merged prep + dec.
//   b <  1024 : Ee [4096][128] f16 = [eh|e2], sqr, zero counts
//   b <  1040 : W_send -> Wh/Wl [64][1024] f16 (transposed, split)
//   b >= 1040 : D = emb @ W_recv + b_recv  (512 blocks)
__global__ __launch_bounds__(256) void k_prep(const float* __restrict__ emb,
                                              const float* __restrict__ Ws,
                                              const float* __restrict__ Wr,
                                              const float* __restrict__ br,
                                              _Float16* __restrict__ Ee,
                                              float* __restrict__ sqr,
                                              _Float16* __restrict__ Wh,
                                              _Float16* __restrict__ Wl,
                                              float* __restrict__ D,
                                              int* __restrict__ counts) {
    int b = blockIdx.x;
    int tid = threadIdx.x;
    if (b < 1024) {
        int code = b * 4 + (tid >> 6);
        int lane = tid & 63;
        float v = emb[(size_t)code * DC + lane];
        _Float16 eh = (_Float16)v;
        _Float16 e2 = (_Float16)((v - (float)eh) * 1024.0f);
        _Float16* row = Ee + (size_t)code * 128;
        row[lane]      = eh;
        row[64 + lane] = e2;
        float s = v * v;
        #pragma unroll
        for (int m = 1; m < 64; m <<= 1) s += __shfl_xor(s, m);
        if (lane == 0) sqr[code] = s;
        if (tid < 4) counts[b * 4 + tid] = 0;
        return;
    }
    if (b < 1040) {
        int k0 = (b - 1024) * 64;
        #pragma unroll
        for (int it = 0; it < 16; ++it) {
            int q = it * 256 + tid;          // 4096 = 64c x 64k
            int c = q >> 6, kl = q & 63;
            float v = Ws[(size_t)(k0 + kl) * 64 + c];
            _Float16 h = (_Float16)v;
            _Float16 l = (_Float16)((v - (float)h) * 1024.0f);
            Wh[(size_t)c * 1024 + k0 + kl] = h;
            Wl[(size_t)c * 1024 + k0 + kl] = l;
        }
        return;
    }
    // ---- decoder codebook: D = emb @ W_recv + b_recv ----
    __shared__ float Ek[64][68];    // [dim][code]
    __shared__ float Wt[64][132];   // [dim][col]
    int bb = b - 1040;
    int cb0  = (bb & 63) * 64;
    int col0 = (bb >> 6) * 128;
    int tx = tid & 15;
    int ty = tid >> 4;

    for (int q = tid; q < 1024; q += 256) {
        int r = q >> 4, c4 = q & 15;
        float4 v = *(const float4*)&emb[(size_t)(cb0 + r) * DC + c4*4];
        Ek[c4*4+0][r] = v.x; Ek[c4*4+1][r] = v.y;
        Ek[c4*4+2][r] = v.z; Ek[c4*4+3][r] = v.w;
    }
    for (int q = tid; q < 2048; q += 256) {
        int c = q >> 5, k4 = q & 31;
        *(float4*)&Wt[c][k4*4] = *(const float4*)&Wr[(size_t)c * DIN + col0 + k4*4];
    }
    __syncthreads();

    float acc[4][8] = {};
    #pragma unroll 8
    for (int c = 0; c < 64; ++c) {
        float4 av = *(const float4*)&Ek[c][tx*4];
        float4 w0 = *(const float4*)&Wt[c][ty*8];
        float4 w1 = *(const float4*)&Wt[c][ty*8 + 4];
        float a[4] = {av.x, av.y, av.z, av.w};
        float w[8] = {w0.x, w0.y, w0.z, w0.w, w1.x, w1.y, w1.z, w1.w};
        #pragma unroll
        for (int i = 0; i < 4; ++i)
            #pragma unroll
            for (int j = 0; j < 8; ++j)
                acc[i][j] += a[i] * w[j];
    }

    #pragma unroll
    for (int i = 0; i < 4; ++i) {
        int code = cb0 + tx*4 + i;
        float4 o0, o1;
        o0.x = acc[i][0] + br[col0 + ty*8 + 0];
        o0.y = acc[i][1] + br[col0 + ty*8 + 1];
        o0.z = acc[i][2] + br[col0 + ty*8 + 2];
        o0.w = acc[i][3] + br[col0 + ty*8 + 3];
        o1.x = acc[i][4] + br[col0 + ty*8 + 4];
        o1.y = acc[i][5] + br[col0 + ty*8 + 5];
        o1.z = acc[i][6] + br[col0 + ty*8 + 6];
        o1.w = acc[i][7] + br[col0 + ty*8 + 7];
        *(float4*)&D[(size_t)code * DIN + col0 + ty*8]     = o0;
        *(float4*)&D[(size_t)code * DIN + col0 + ty*8 + 4] = o1;
    }
}

// ---------------------------------------------------------------------------
// z = input @ W_send + b_send via split-f16 MFMA; emits Ze [32768][128] = [z2|zh].
__global__ __launch_bounds__(256) void k_send(const float* __restrict__ in,
                                              const _Float16* __restrict__ Wh,
                                              const _Float16* __restrict__ Wl,
                                              const float* __restrict__ bs,
                                              _Float16* __restrict__ Ze) {
    __shared__ char smem[65536];
    const int tid = threadIdx.x;
    const int row0 = blockIdx.x * 64;
    const int wid = tid >> 6, lane = tid & 63;
    const int c15 = lane & 15, g = lane >> 4;
    const int wm = wid >> 1, wn = wid & 1;

    f32x4 accH[2][2], accL[2][2];
    const f32x4 z4 = {0.f, 0.f, 0.f, 0.f};
    #pragma unroll
    for (int mf = 0; mf < 2; ++mf)
        #pragma unroll
        for (int nf = 0; nf < 2; ++nf) { accH[mf][nf] = z4; accL[mf][nf] = z4; }

    int abyte[2], aswz[2], bbyte[2], bswz[2];
    #pragma unroll
    for (int mf = 0; mf < 2; ++mf) {
        int r = wm * 32 + mf * 16 + c15;
        abyte[mf] = r * 128; aswz[mf] = (r & 7) << 4;
    }
    #pragma unroll
    for (int nf = 0; nf < 2; ++nf) {
        int c = wn * 32 + nf * 16 + c15;
        bbyte[nf] = c * 128; bswz[nf] = (c & 7) << 4;
    }
    const int g16 = g * 16;

    auto stageB = [&](int buf, int s) {
        char* dst = smem + buf * 32768 + 16384;
        #pragma unroll
        for (int r = 0; r < 2; ++r) {
            int p = r * 4096 + wid * 1024 + lane * 16;
            int row = p >> 7, off = p & 127;
            int soff = off ^ ((row & 7) << 4);
            gll16((const char*)Wh + (size_t)row * 2048 + s * 128 + soff,
                  dst + r * 4096 + wid * 1024);
        }
        #pragma unroll
        for (int r = 0; r < 2; ++r) {
            int p = r * 4096 + wid * 1024 + lane * 16;
            int row = p >> 7, off = p & 127;
            int soff = off ^ ((row & 7) << 4);
            gll16((const char*)Wl + (size_t)row * 2048 + s * 128 + soff,
                  dst + 8192 + r * 4096 + wid * 1024);
        }
    };

    auto loadA = [&](int s, float4* a) {
        #pragma unroll
        for (int it = 0; it < 4; ++it) {
            int q = it * 256 + tid;
            int r = q >> 4, c4 = q & 15;
            a[it] = *(const float4*)&in[(size_t)(row0 + r) * DIN + s * 64 + c4 * 4];
        }
    };

    auto writeA = [&](int buf, const float4* a) {
        char* Ah = smem + buf * 32768;
        char* Al = Ah + 8192;
        #pragma unroll
        for (int it = 0; it < 4; ++it) {
            int q = it * 256 + tid;
            int r = q >> 4, c4 = q & 15;
            float v[4] = {a[it].x, a[it].y, a[it].z, a[it].w};
            f16x4 h, l;
            #pragma unroll
            for (int j = 0; j < 4; ++j) {
                _Float16 hh = (_Float16)v[j];
                h[j] = hh;
                l[j] = (_Float16)((v[j] - (float)hh) * 1024.0f);
            }
            int o = r * 128 + ((c4 * 8) ^ ((r & 7) << 4));
            *(f16x4*)(Ah + o) = h;
            *(f16x4*)(Al + o) = l;
        }
    };

    auto compute = [&](int buf) {
        const char* Ah = smem + buf * 32768;
        const char* Al = Ah + 8192;
        const char* Bh = Ah + 16384;
        const char* Bl = Ah + 24576;
        #pragma unroll
        for (int ks = 0; ks < 2; ++ks) {
            int koff = ks * 64 + g16;
            f16x8 bh[2], bl[2];
            #pragma unroll
            for (int nf = 0; nf < 2; ++nf) {
                bh[nf] = *(const f16x8*)(Bh + bbyte[nf] + (koff ^ bswz[nf]));
                bl[nf] = *(const f16x8*)(Bl + bbyte[nf] + (koff ^ bswz[nf]));
            }
            #pragma unroll
            for (int mf = 0; mf < 2; ++mf) {
                f16x8 ah = *(const f16x8*)(Ah + abyte[mf] + (koff ^ aswz[mf]));
                f16x8 al = *(const f16x8*)(Al + abyte[mf] + (koff ^ aswz[mf]));
                #pragma unroll
                for (int nf = 0; nf < 2; ++nf) {
                    accH[mf][nf] = __builtin_amdgcn_mfma_f32_16x16x32_f16(
                        ah, bh[nf], accH[mf][nf], 0, 0, 0);
                    accL[mf][nf] = __builtin_amdgcn_mfma_f32_16x16x32_f16(
                        ah, bl[nf], accL[mf][nf], 0, 0, 0);
                    accL[mf][nf] = __builtin_amdgcn_mfma_f32_16x16x32_f16(
                        al, bh[nf], accL[mf][nf], 0, 0, 0);
                }
            }
        }
    };

    {
        float4 a0[4];
        loadA(0, a0);
        stageB(0, 0);
        writeA(0, a0);
    }
    __syncthreads();

    for (int s = 0; s < 16; ++s) {
        int c = s & 1;
        float4 an[4];
        if (s < 15) {
            loadA(s + 1, an);
            stageB(c ^ 1, s + 1);
        }
        compute(c);
        if (s < 15) writeA(c ^ 1, an);
        __syncthreads();
    }

    // epilogue: z = accH + accL/1024 + bias -> [z2|zh] f16 -> Ze
    #pragma unroll
    for (int nf = 0; nf < 2; ++nf) {
        int col = wn * 32 + nf * 16 + c15;
        float bias = bs[col];
        #pragma unroll
        for (int mf = 0; mf < 2; ++mf) {
            #pragma unroll
            for (int r2 = 0; r2 < 4; ++r2) {
                float zv = accH[mf][nf][r2] + accL[mf][nf][r2] * 0.0009765625f + bias;
                _Float16 zh = (_Float16)zv;
                _Float16 z2 = (_Float16)((zv - (float)zh) * 1024.0f);
                int row = row0 + wm * 32 + mf * 16 + g * 4 + r2;
                _Float16* zr = Ze + (size_t)row * 128;
                zr[col]      = z2;
                zr[64 + col] = zh;
            }
        }
    }
}

// ---------------------------------------------------------------------------
// Persistent-Z score kernel + fused loss + fused gather.
// After the argmin, winning codes live in LDS; the block copies D[code] rows
// (L2/L3-resident) straight to x — no idx round-trip, no gather dispatch.
__global__ __launch_bounds__(512, 2) void k_score(const _Float16* __restrict__ Ee,
                                                  const _Float16* __restrict__ Ze,
                                                  const float* __restrict__ sqr,
                                                  const float* __restrict__ D,
                                                  float* __restrict__ x,
                                                  float* __restrict__ out_idx,
                                                  int* __restrict__ counts,
                                                  float* __restrict__ lpart) {
    __shared__ char smem[71168];          // 2x32KB E dbuf + reduce + sidx
    const int tid = threadIdx.x;
    const int row0 = blockIdx.x * 128;
    const int wid = tid >> 6, lane = tid & 63;
    const int c15 = lane & 15, g = lane >> 4;
    const int wm = wid >> 1;              // 0..3 : codes wm*32..+31
    const int wn = wid & 1;               // 0..1 : rows  wn*64..+63
    const int g16 = g * 16;

    // ---- Z fragments: load once from global into registers ----
    f16x8 zf2[2][4], zfh[2][4];           // [kstep j][nf]
    #pragma unroll
    for (int nf = 0; nf < 4; ++nf) {
        const _Float16* zr = Ze + (size_t)(row0 + wn * 64 + nf * 16 + c15) * 128;
        #pragma unroll
        for (int j = 0; j < 2; ++j) {
            zf2[j][nf] = *(const f16x8*)(zr + j * 32 + g * 8);        // z2
            zfh[j][nf] = *(const f16x8*)(zr + 64 + j * 32 + g * 8);   // zh
        }
    }

    int rbase[2], rx[2];
    #pragma unroll
    for (int mf = 0; mf < 2; ++mf) {
        int r = wm * 32 + mf * 16 + c15;
        rbase[mf] = r * 256;
        rx[mf] = (r & 15) << 4;
    }

    auto stage = [&](int ch, int buf) {
        char* dst = smem + buf * 32768;
        const char* src = (const char*)Ee + (size_t)ch * 32768;
        #pragma unroll
        for (int t = 0; t < 4; ++t) {
            int p = t * 8192 + tid * 16;
            int r = p >> 8, b = p & 255;
            gll16(src + r * 256 + (b ^ ((r & 15) << 4)), dst + p);
        }
    };

    float bv[4];
    int   bi[4];
    #pragma unroll
    for (int nf = 0; nf < 4; ++nf) { bv[nf] = 3.402823466e38f; bi[nf] = 0; }

    const f32x4 zz4 = {0.f, 0.f, 0.f, 0.f};
    static const int koffs[6] = {0, 64, 128, 192, 0, 64};

    stage(0, 0);
    __syncthreads();

    for (int ch = 0; ch < 32; ++ch) {
        const int buf = ch & 1;
        f32x4 sqv[2];
        #pragma unroll
        for (int mf = 0; mf < 2; ++mf)
            sqv[mf] = *(const f32x4*)(sqr + ch * 128 + wm * 32 + mf * 16 + g * 4);

        if (ch < 31) stage(ch + 1, buf ^ 1);

        const char* base = smem + buf * 32768;
        f32x4 accL[2][4], accH[2][4];
        #pragma unroll
        for (int j = 0; j < 6; ++j) {
            const int kraw = koffs[j] + g16;
            f16x8 af[2];
            #pragma unroll
            for (int mf = 0; mf < 2; ++mf)
                af[mf] = *(const f16x8*)(base + rbase[mf] + (kraw ^ rx[mf]));
            #pragma unroll
            for (int mf = 0; mf < 2; ++mf) {
                #pragma unroll
                for (int nf = 0; nf < 4; ++nf) {
                    if (j == 0)
                        accL[mf][nf] = __builtin_amdgcn_mfma_f32_16x16x32_f16(
                            af[mf], zf2[0][nf], zz4, 0, 0, 0);
                    else if (j == 1)
                        accL[mf][nf] = __builtin_amdgcn_mfma_f32_16x16x32_f16(
                            af[mf], zf2[1][nf], accL[mf][nf], 0, 0, 0);
                    else if (j < 4)
                        accL[mf][nf] = __builtin_amdgcn_mfma_f32_16x16x32_f16(
                            af[mf], zfh[j - 2][nf], accL[mf][nf], 0, 0, 0);
                    else if (j == 4)
                        accH[mf][nf] = __builtin_amdgcn_mfma_f32_16x16x32_f16(
                            af[mf], zfh[0][nf], zz4, 0, 0, 0);
                    else
                        accH[mf][nf] = __builtin_amdgcn_mfma_f32_16x16x32_f16(
                            af[mf], zfh[1][nf], accH[mf][nf], 0, 0, 0);
                }
            }
        }

        #pragma unroll
        for (int nf = 0; nf < 4; ++nf) {
            #pragma unroll
            for (int mf = 0; mf < 2; ++mf) {
                f32x4 v = sqv[mf] - accH[mf][nf] * 2.0f
                                  - accL[mf][nf] * 0.001953125f;
                #pragma unroll
                for (int r2 = 0; r2 < 4; ++r2) {
                    if (v[r2] < bv[nf]) {
                        bv[nf] = v[r2];
                        bi[nf] = ch * 128 + wm * 32 + mf * 16 + g * 4 + r2;
                    }
                }
            }
        }
        __syncthreads();
    }

    // ---- final reduction: argmin + ||z||^2 + loss partial + sidx ----
    float* redv = (float*)(smem + 65536);          // [4][128]
    int*   redi = (int*)(smem + 65536 + 2048);     // [4][128]
    float* zsqa = (float*)(smem + 65536 + 4096);   // [128]
    int*   sidx = (int*)(smem + 65536 + 4608);     // [128]

    #pragma unroll
    for (int nf = 0; nf < 4; ++nf) {
        float v_ = bv[nf]; int i_ = bi[nf];
        #pragma unroll
        for (int m = 16; m <= 32; m <<= 1) {
            float ov = __shfl_xor(v_, m);
            int oi = __shfl_xor(i_, m);
            if (ov < v_ || (ov == v_ && oi < i_)) { v_ = ov; i_ = oi; }
        }
        if (g == 0) {
            int rl = wn * 64 + nf * 16 + c15;
            redv[wm * 128 + rl] = v_;
            redi[wm * 128 + rl] = i_;
        }
    }
    // ||z||^2 per row: identical regs across wm-waves; use wm==0 only
    if (wm == 0) {
        #pragma unroll
        for (int nf = 0; nf < 4; ++nf) {
            float s = 0.f;
            #pragma unroll
            for (int j = 0; j < 2; ++j)
                #pragma unroll
                for (int e = 0; e < 8; ++e) {
                    float zv = (float)zfh[j][nf][e]
                             + (float)zf2[j][nf][e] * 0.0009765625f;
                    s += zv * zv;
                }
            s += __shfl_xor(s, 16);
            s += __shfl_xor(s, 32);
            if (g == 0) zsqa[wn * 64 + nf * 16 + c15] = s;
        }
    }
    __syncthreads();
    float lossv = 0.f;
    if (tid < 128) {
        float v0 = redv[tid]; int i0 = redi[tid];
        #pragma unroll
        for (int w = 1; w < 4; ++w) {
            float v1 = redv[w * 128 + tid]; int i1 = redi[w * 128 + tid];
            if (v1 < v0 || (v1 == v0 && i1 < i0)) { v0 = v1; i0 = i1; }
        }
        int grow = row0 + tid;
        out_idx[grow] = (float)i0;
        sidx[tid] = i0;
        atomicAdd(&counts[i0], 1);
        lossv = v0 + zsqa[tid];
    }
    __syncthreads();   // sidx visible to all waves
    // block-sum the 128 loss values (waves 0,1 hold them)
    #pragma unroll
    for (int m = 1; m < 64; m <<= 1) lossv += __shfl_xor(lossv, m);
    if (tid == 0)  redv[0] = lossv;
    if (tid == 64) redv[1] = lossv;

    // ---- fused gather: x[row] = D[sidx[row]] ----
    #pragma unroll 4
    for (int rr = 0; rr < 16; ++rr) {
        int r = wid * 16 + rr;
        int code = sidx[r];
        const float4* src = (const float4*)(D + (size_t)code * DIN);
        float4* dst = (float4*)(x + (size_t)(row0 + r) * DIN);
        #pragma unroll
        for (int q = 0; q < 4; ++q)
            dst[q * 64 + lane] = src[q * 64 + lane];
    }

    __syncthreads();
    if (tid == 0) lpart[blockIdx.x] = redv[0] + redv[1];
}

// ---------------------------------------------------------------------------
__global__ __launch_bounds__(256) void k_final(const int* __restrict__ counts,
                                               const float* __restrict__ partials,
                                               float* __restrict__ out_sc) {
    __shared__ float red[256];
    int tid = threadIdx.x;

    red[tid] = partials[tid];
    __syncthreads();
    for (int s = 128; s > 0; s >>= 1) {
        if (tid < s) red[tid] += red[tid + s];
        __syncthreads();
    }
    float loss = red[0];
    __syncthreads();

    float ep = 0.f;
    for (int k = tid; k < KC; k += 256) {
        int c = counts[k];
        if (c > 0) {
            float p = (float)c / 32768.0f;
            ep += p * logf(p);
        }
    }
    red[tid] = ep; __syncthreads();
    for (int s = 128; s > 0; s >>= 1) {
        if (tid < s) red[tid] += red[tid + s];
        __syncthreads();
    }
    if (tid == 0) {
        out_sc[0] = loss;
        out_sc[1] = loss;
        out_sc[2] = -red[0] * 1.4426950408889634f;
    }
}

// ---------------------------------------------------------------------------
extern "C" void kernel_launch(void* const* d_in, const int* in_sizes, int n_in,
                              void* d_out, int out_size, void* d_ws, size_t ws_size,
                              hipStream_t stream) {
    (void)in_sizes; (void)n_in; (void)out_size; (void)ws_size;
    const float* input  = (const float*)d_in[0];
    const float* W_send = (const float*)d_in[1];
    const float* b_send = (const float*)d_in[2];
    const float* emb    = (const float*)d_in[3];
    const float* W_recv = (const float*)d_in[4];
    const float* b_recv = (const float*)d_in[5];
    float* out = (float*)d_out;

    char* ws = (char*)d_ws;
    _Float16* Ze  = (_Float16*)(ws);                  //  8 MB  [32768][128]
    float*    D   = (float*)(ws + 8388608);           // 16 MB
    _Float16* Ee  = (_Float16*)(ws + 25165824);       //  1 MB  [4096][128]
    float*    sqr = (float*)(ws + 26214400);          // 16 KB
    int*   counts = (int*)  (ws + 26361856);          // 16 KB
    float* lpart  = (float*)(ws + 26378240);          //  1 KB (256 floats)
    _Float16* Wh  = (_Float16*)(ws + 26379264);       // 128 KB [64][1024]
    _Float16* Wl  = (_Float16*)(ws + 26510336);       // 128 KB [64][1024]

    float* out_x   = out;                    // 33554432
    float* out_idx = out + 33554432;         // 32768
    float* out_sc  = out + 33587200;         // 3

    k_prep<<<1552, 256, 0, stream>>>(emb, W_send, W_recv, b_recv,
                                     Ee, sqr, Wh, Wl, D, counts);
    k_send<<<512, 256, 0, stream>>>(input, Wh, Wl, b_send, Ze);
    k_score<<<256, 512, 0, stream>>>(Ee, Ze, sqr, D, out_x, out_idx, counts, lpart);
    k_final<<<1, 256, 0, stream>>>(counts, lpart, out_sc);
}

// Round 9
// 120.954 us; speedup vs baseline: 1.2981x; 1.2981x over previous
//
#include <hip/hip_runtime.h>

#define DIN 1024
#define DC 64
#define KC 4096

typedef _Float16 f16x8 __attribute__((ext_vector_type(8)));
typedef _Float16 f16x4 __attribute__((ext_vector_type(4)));
typedef float f32x4 __attribute__((ext_vector_type(4)));

__device__ __forceinline__ void gll16(const void* g, void* l) {
    __builtin_amdgcn_global_load_lds(
        (const __attribute__((address_space(1))) unsigned int*)g,
        (__attribute__((address_space(3))) unsigned int*)l, 16, 0, 0);
}

// ---------------------------------------------------------------------------
// Merged prep + dec.
//   b <  1024 : Ee [4096][128] f16 = [eh|e2], sqr, zero counts
//   b <  1040 : W_send -> Wh/Wl [64][1024] f16 (transposed, split)
//   b >= 1040 : D = emb @ W_recv + b_recv  (512 blocks)
__global__ __launch_bounds__(256) void k_prep(const float* __restrict__ emb,
                                              const float* __restrict__ Ws,
                                              const float* __restrict__ Wr,
                                              const float* __restrict__ br,
                                              _Float16* __restrict__ Ee,
                                              float* __restrict__ sqr,
                                              _Float16* __restrict__ Wh,
                                              _Float16* __restrict__ Wl,
                                              float* __restrict__ D,
                                              int* __restrict__ counts) {
    int b = blockIdx.x;
    int tid = threadIdx.x;
    if (b < 1024) {
        int code = b * 4 + (tid >> 6);
        int lane = tid & 63;
        float v = emb[(size_t)code * DC + lane];
        _Float16 eh = (_Float16)v;
        _Float16 e2 = (_Float16)((v - (float)eh) * 1024.0f);
        _Float16* row = Ee + (size_t)code * 128;
        row[lane]      = eh;
        row[64 + lane] = e2;
        float s = v * v;
        #pragma unroll
        for (int m = 1; m < 64; m <<= 1) s += __shfl_xor(s, m);
        if (lane == 0) sqr[code] = s;
        if (tid < 4) counts[b * 4 + tid] = 0;
        return;
    }
    if (b < 1040) {
        int k0 = (b - 1024) * 64;
        #pragma unroll
        for (int it = 0; it < 16; ++it) {
            int q = it * 256 + tid;          // 4096 = 64c x 64k
            int c = q >> 6, kl = q & 63;
            float v = Ws[(size_t)(k0 + kl) * 64 + c];
            _Float16 h = (_Float16)v;
            _Float16 l = (_Float16)((v - (float)h) * 1024.0f);
            Wh[(size_t)c * 1024 + k0 + kl] = h;
            Wl[(size_t)c * 1024 + k0 + kl] = l;
        }
        return;
    }
    // ---- decoder codebook: D = emb @ W_recv + b_recv ----
    __shared__ float Ek[64][68];    // [dim][code]
    __shared__ float Wt[64][132];   // [dim][col]
    int bb = b - 1040;
    int cb0  = (bb & 63) * 64;
    int col0 = (bb >> 6) * 128;
    int tx = tid & 15;
    int ty = tid >> 4;

    for (int q = tid; q < 1024; q += 256) {
        int r = q >> 4, c4 = q & 15;
        float4 v = *(const float4*)&emb[(size_t)(cb0 + r) * DC + c4*4];
        Ek[c4*4+0][r] = v.x; Ek[c4*4+1][r] = v.y;
        Ek[c4*4+2][r] = v.z; Ek[c4*4+3][r] = v.w;
    }
    for (int q = tid; q < 2048; q += 256) {
        int c = q >> 5, k4 = q & 31;
        *(float4*)&Wt[c][k4*4] = *(const float4*)&Wr[(size_t)c * DIN + col0 + k4*4];
    }
    __syncthreads();

    float acc[4][8] = {};
    #pragma unroll 8
    for (int c = 0; c < 64; ++c) {
        float4 av = *(const float4*)&Ek[c][tx*4];
        float4 w0 = *(const float4*)&Wt[c][ty*8];
        float4 w1 = *(const float4*)&Wt[c][ty*8 + 4];
        float a[4] = {av.x, av.y, av.z, av.w};
        float w[8] = {w0.x, w0.y, w0.z, w0.w, w1.x, w1.y, w1.z, w1.w};
        #pragma unroll
        for (int i = 0; i < 4; ++i)
            #pragma unroll
            for (int j = 0; j < 8; ++j)
                acc[i][j] += a[i] * w[j];
    }

    #pragma unroll
    for (int i = 0; i < 4; ++i) {
        int code = cb0 + tx*4 + i;
        float4 o0, o1;
        o0.x = acc[i][0] + br[col0 + ty*8 + 0];
        o0.y = acc[i][1] + br[col0 + ty*8 + 1];
        o0.z = acc[i][2] + br[col0 + ty*8 + 2];
        o0.w = acc[i][3] + br[col0 + ty*8 + 3];
        o1.x = acc[i][4] + br[col0 + ty*8 + 4];
        o1.y = acc[i][5] + br[col0 + ty*8 + 5];
        o1.z = acc[i][6] + br[col0 + ty*8 + 6];
        o1.w = acc[i][7] + br[col0 + ty*8 + 7];
        *(float4*)&D[(size_t)code * DIN + col0 + ty*8]     = o0;
        *(float4*)&D[(size_t)code * DIN + col0 + ty*8 + 4] = o1;
    }
}

// ---------------------------------------------------------------------------
// z = input @ W_send + b_send via split-f16 MFMA; emits Ze [32768][128] = [z2|zh].
__global__ __launch_bounds__(256) void k_send(const float* __restrict__ in,
                                              const _Float16* __restrict__ Wh,
                                              const _Float16* __restrict__ Wl,
                                              const float* __restrict__ bs,
                                              _Float16* __restrict__ Ze) {
    __shared__ char smem[65536];
    const int tid = threadIdx.x;
    const int row0 = blockIdx.x * 64;
    const int wid = tid >> 6, lane = tid & 63;
    const int c15 = lane & 15, g = lane >> 4;
    const int wm = wid >> 1, wn = wid & 1;

    f32x4 accH[2][2], accL[2][2];
    const f32x4 z4 = {0.f, 0.f, 0.f, 0.f};
    #pragma unroll
    for (int mf = 0; mf < 2; ++mf)
        #pragma unroll
        for (int nf = 0; nf < 2; ++nf) { accH[mf][nf] = z4; accL[mf][nf] = z4; }

    int abyte[2], aswz[2], bbyte[2], bswz[2];
    #pragma unroll
    for (int mf = 0; mf < 2; ++mf) {
        int r = wm * 32 + mf * 16 + c15;
        abyte[mf] = r * 128; aswz[mf] = (r & 7) << 4;
    }
    #pragma unroll
    for (int nf = 0; nf < 2; ++nf) {
        int c = wn * 32 + nf * 16 + c15;
        bbyte[nf] = c * 128; bswz[nf] = (c & 7) << 4;
    }
    const int g16 = g * 16;

    auto stageB = [&](int buf, int s) {
        char* dst = smem + buf * 32768 + 16384;
        #pragma unroll
        for (int r = 0; r < 2; ++r) {
            int p = r * 4096 + wid * 1024 + lane * 16;
            int row = p >> 7, off = p & 127;
            int soff = off ^ ((row & 7) << 4);
            gll16((const char*)Wh + (size_t)row * 2048 + s * 128 + soff,
                  dst + r * 4096 + wid * 1024);
        }
        #pragma unroll
        for (int r = 0; r < 2; ++r) {
            int p = r * 4096 + wid * 1024 + lane * 16;
            int row = p >> 7, off = p & 127;
            int soff = off ^ ((row & 7) << 4);
            gll16((const char*)Wl + (size_t)row * 2048 + s * 128 + soff,
                  dst + 8192 + r * 4096 + wid * 1024);
        }
    };

    auto loadA = [&](int s, float4* a) {
        #pragma unroll
        for (int it = 0; it < 4; ++it) {
            int q = it * 256 + tid;
            int r = q >> 4, c4 = q & 15;
            a[it] = *(const float4*)&in[(size_t)(row0 + r) * DIN + s * 64 + c4 * 4];
        }
    };

    auto writeA = [&](int buf, const float4* a) {
        char* Ah = smem + buf * 32768;
        char* Al = Ah + 8192;
        #pragma unroll
        for (int it = 0; it < 4; ++it) {
            int q = it * 256 + tid;
            int r = q >> 4, c4 = q & 15;
            float v[4] = {a[it].x, a[it].y, a[it].z, a[it].w};
            f16x4 h, l;
            #pragma unroll
            for (int j = 0; j < 4; ++j) {
                _Float16 hh = (_Float16)v[j];
                h[j] = hh;
                l[j] = (_Float16)((v[j] - (float)hh) * 1024.0f);
            }
            int o = r * 128 + ((c4 * 8) ^ ((r & 7) << 4));
            *(f16x4*)(Ah + o) = h;
            *(f16x4*)(Al + o) = l;
        }
    };

    auto compute = [&](int buf) {
        const char* Ah = smem + buf * 32768;
        const char* Al = Ah + 8192;
        const char* Bh = Ah + 16384;
        const char* Bl = Ah + 24576;
        #pragma unroll
        for (int ks = 0; ks < 2; ++ks) {
            int koff = ks * 64 + g16;
            f16x8 bh[2], bl[2];
            #pragma unroll
            for (int nf = 0; nf < 2; ++nf) {
                bh[nf] = *(const f16x8*)(Bh + bbyte[nf] + (koff ^ bswz[nf]));
                bl[nf] = *(const f16x8*)(Bl + bbyte[nf] + (koff ^ bswz[nf]));
            }
            #pragma unroll
            for (int mf = 0; mf < 2; ++mf) {
                f16x8 ah = *(const f16x8*)(Ah + abyte[mf] + (koff ^ aswz[mf]));
                f16x8 al = *(const f16x8*)(Al + abyte[mf] + (koff ^ aswz[mf]));
                #pragma unroll
                for (int nf = 0; nf < 2; ++nf) {
                    accH[mf][nf] = __builtin_amdgcn_mfma_f32_16x16x32_f16(
                        ah, bh[nf], accH[mf][nf], 0, 0, 0);
                    accL[mf][nf] = __builtin_amdgcn_mfma_f32_16x16x32_f16(
                        ah, bl[nf], accL[mf][nf], 0, 0, 0);
                    accL[mf][nf] = __builtin_amdgcn_mfma_f32_16x16x32_f16(
                        al, bh[nf], accL[mf][nf], 0, 0, 0);
                }
            }
        }
    };

    {
        float4 a0[4];
        loadA(0, a0);
        stageB(0, 0);
        writeA(0, a0);
    }
    __syncthreads();

    for (int s = 0; s < 16; ++s) {
        int c = s & 1;
        float4 an[4];
        if (s < 15) {
            loadA(s + 1, an);
            stageB(c ^ 1, s + 1);
        }
        compute(c);
        if (s < 15) writeA(c ^ 1, an);
        __syncthreads();
    }

    // epilogue: z = accH + accL/1024 + bias -> [z2|zh] f16 -> Ze
    #pragma unroll
    for (int nf = 0; nf < 2; ++nf) {
        int col = wn * 32 + nf * 16 + c15;
        float bias = bs[col];
        #pragma unroll
        for (int mf = 0; mf < 2; ++mf) {
            #pragma unroll
            for (int r2 = 0; r2 < 4; ++r2) {
                float zv = accH[mf][nf][r2] + accL[mf][nf][r2] * 0.0009765625f + bias;
                _Float16 zh = (_Float16)zv;
                _Float16 z2 = (_Float16)((zv - (float)zh) * 1024.0f);
                int row = row0 + wm * 32 + mf * 16 + g * 4 + r2;
                _Float16* zr = Ze + (size_t)row * 128;
                zr[col]      = z2;
                zr[64 + col] = zh;
            }
        }
    }
}

// ---------------------------------------------------------------------------
// Persistent-Z score kernel + fused loss. Grid 512 x 512 thr; block = 64 rows
// (2 blocks/CU for occupancy). Z-frags in registers; E double-buffered in LDS.
__global__ __launch_bounds__(512, 2) void k_score(const _Float16* __restrict__ Ee,
                                                  const _Float16* __restrict__ Ze,
                                                  const float* __restrict__ sqr,
                                                  int* __restrict__ idx,
                                                  float* __restrict__ out_idx,
                                                  int* __restrict__ counts,
                                                  float* __restrict__ lpart) {
    __shared__ char smem[67840];          // 2x32KB E dbuf + 2.25KB reduce
    const int tid = threadIdx.x;
    const int row0 = blockIdx.x * 64;
    const int wid = tid >> 6, lane = tid & 63;
    const int c15 = lane & 15, g = lane >> 4;
    const int wm = wid >> 1;              // 0..3 : codes wm*32..+31
    const int wn = wid & 1;               // 0..1 : rows  wn*32..+31
    const int g16 = g * 16;

    // ---- Z fragments: load once from global into registers ----
    f16x8 zf2[2][2], zfh[2][2];           // [kstep j][nf]
    #pragma unroll
    for (int nf = 0; nf < 2; ++nf) {
        const _Float16* zr = Ze + (size_t)(row0 + wn * 32 + nf * 16 + c15) * 128;
        #pragma unroll
        for (int j = 0; j < 2; ++j) {
            zf2[j][nf] = *(const f16x8*)(zr + j * 32 + g * 8);        // z2
            zfh[j][nf] = *(const f16x8*)(zr + 64 + j * 32 + g * 8);   // zh
        }
    }

    int rbase[2], rx[2];
    #pragma unroll
    for (int mf = 0; mf < 2; ++mf) {
        int r = wm * 32 + mf * 16 + c15;
        rbase[mf] = r * 256;
        rx[mf] = (r & 15) << 4;
    }

    auto stage = [&](int ch, int buf) {
        char* dst = smem + buf * 32768;
        const char* src = (const char*)Ee + (size_t)ch * 32768;
        #pragma unroll
        for (int t = 0; t < 4; ++t) {
            int p = t * 8192 + tid * 16;
            int r = p >> 8, b = p & 255;
            gll16(src + r * 256 + (b ^ ((r & 15) << 4)), dst + p);
        }
    };

    float bv[2];
    int   bi[2];
    #pragma unroll
    for (int nf = 0; nf < 2; ++nf) { bv[nf] = 3.402823466e38f; bi[nf] = 0; }

    const f32x4 zz4 = {0.f, 0.f, 0.f, 0.f};
    static const int koffs[6] = {0, 64, 128, 192, 0, 64};

    stage(0, 0);
    __syncthreads();

    for (int ch = 0; ch < 32; ++ch) {
        const int buf = ch & 1;
        f32x4 sqv[2];
        #pragma unroll
        for (int mf = 0; mf < 2; ++mf)
            sqv[mf] = *(const f32x4*)(sqr + ch * 128 + wm * 32 + mf * 16 + g * 4);

        if (ch < 31) stage(ch + 1, buf ^ 1);

        const char* base = smem + buf * 32768;
        f32x4 accL[2][2], accH[2][2];
        #pragma unroll
        for (int j = 0; j < 6; ++j) {
            const int kraw = koffs[j] + g16;
            f16x8 af[2];
            #pragma unroll
            for (int mf = 0; mf < 2; ++mf)
                af[mf] = *(const f16x8*)(base + rbase[mf] + (kraw ^ rx[mf]));
            #pragma unroll
            for (int mf = 0; mf < 2; ++mf) {
                #pragma unroll
                for (int nf = 0; nf < 2; ++nf) {
                    if (j == 0)
                        accL[mf][nf] = __builtin_amdgcn_mfma_f32_16x16x32_f16(
                            af[mf], zf2[0][nf], zz4, 0, 0, 0);
                    else if (j == 1)
                        accL[mf][nf] = __builtin_amdgcn_mfma_f32_16x16x32_f16(
                            af[mf], zf2[1][nf], accL[mf][nf], 0, 0, 0);
                    else if (j < 4)
                        accL[mf][nf] = __builtin_amdgcn_mfma_f32_16x16x32_f16(
                            af[mf], zfh[j - 2][nf], accL[mf][nf], 0, 0, 0);
                    else if (j == 4)
                        accH[mf][nf] = __builtin_amdgcn_mfma_f32_16x16x32_f16(
                            af[mf], zfh[0][nf], zz4, 0, 0, 0);
                    else
                        accH[mf][nf] = __builtin_amdgcn_mfma_f32_16x16x32_f16(
                            af[mf], zfh[1][nf], accH[mf][nf], 0, 0, 0);
                }
            }
        }

        #pragma unroll
        for (int nf = 0; nf < 2; ++nf) {
            #pragma unroll
            for (int mf = 0; mf < 2; ++mf) {
                f32x4 v = sqv[mf] - accH[mf][nf] * 2.0f
                                  - accL[mf][nf] * 0.001953125f;
                #pragma unroll
                for (int r2 = 0; r2 < 4; ++r2) {
                    if (v[r2] < bv[nf]) {
                        bv[nf] = v[r2];
                        bi[nf] = ch * 128 + wm * 32 + mf * 16 + g * 4 + r2;
                    }
                }
            }
        }
        __syncthreads();
    }

    // ---- final reduction: argmin + ||z||^2 + loss partial ----
    float* redv = (float*)(smem + 65536);          // [4][64]
    int*   redi = (int*)(smem + 65536 + 1024);     // [4][64]
    float* zsqa = (float*)(smem + 65536 + 2048);   // [64]

    #pragma unroll
    for (int nf = 0; nf < 2; ++nf) {
        float v_ = bv[nf]; int i_ = bi[nf];
        #pragma unroll
        for (int m = 16; m <= 32; m <<= 1) {
            float ov = __shfl_xor(v_, m);
            int oi = __shfl_xor(i_, m);
            if (ov < v_ || (ov == v_ && oi < i_)) { v_ = ov; i_ = oi; }
        }
        if (g == 0) {
            int rl = wn * 32 + nf * 16 + c15;
            redv[wm * 64 + rl] = v_;
            redi[wm * 64 + rl] = i_;
        }
    }
    // ||z||^2 per row: identical regs across wm-waves; use wm==0 only
    if (wm == 0) {
        #pragma unroll
        for (int nf = 0; nf < 2; ++nf) {
            float s = 0.f;
            #pragma unroll
            for (int j = 0; j < 2; ++j)
                #pragma unroll
                for (int e = 0; e < 8; ++e) {
                    float zv = (float)zfh[j][nf][e]
                             + (float)zf2[j][nf][e] * 0.0009765625f;
                    s += zv * zv;
                }
            s += __shfl_xor(s, 16);
            s += __shfl_xor(s, 32);
            if (g == 0) zsqa[wn * 32 + nf * 16 + c15] = s;
        }
    }
    __syncthreads();
    float lossv = 0.f;
    if (tid < 64) {
        float v0 = redv[tid]; int i0 = redi[tid];
        #pragma unroll
        for (int w = 1; w < 4; ++w) {
            float v1 = redv[w * 64 + tid]; int i1 = redi[w * 64 + tid];
            if (v1 < v0 || (v1 == v0 && i1 < i0)) { v0 = v1; i0 = i1; }
        }
        int grow = row0 + tid;
        idx[grow] = i0;
        out_idx[grow] = (float)i0;
        atomicAdd(&counts[i0], 1);
        lossv = v0 + zsqa[tid];
        // wave-0 reduce (64 lanes hold all 64 rows' losses)
        #pragma unroll
        for (int m = 1; m < 64; m <<= 1) lossv += __shfl_xor(lossv, m);
        if (tid == 0) lpart[blockIdx.x] = lossv;
    }
}

// ---------------------------------------------------------------------------
// x[s] = D[idx[s]]  grid-stride over 2M float4s (high-occupancy flush)
__global__ __launch_bounds__(256) void k_gather(const float* __restrict__ D,
                                                const int* __restrict__ idx,
                                                float* __restrict__ x) {
    int gidx = blockIdx.x * 256 + threadIdx.x;
    #pragma unroll
    for (int it = 0; it < 4; ++it) {
        int f = gidx + it * 524288;
        int row = f >> 6, c = f & 63;
        int code = idx[row];
        *(float4*)&x[(size_t)row * DIN + c*4] =
            *(const float4*)&D[(size_t)code * DIN + c*4];
    }
}

// ---------------------------------------------------------------------------
__global__ __launch_bounds__(256) void k_final(const int* __restrict__ counts,
                                               const float* __restrict__ partials,
                                               float* __restrict__ out_sc) {
    __shared__ float red[256];
    int tid = threadIdx.x;

    red[tid] = partials[tid] + partials[256 + tid];
    __syncthreads();
    for (int s = 128; s > 0; s >>= 1) {
        if (tid < s) red[tid] += red[tid + s];
        __syncthreads();
    }
    float loss = red[0];
    __syncthreads();

    float ep = 0.f;
    for (int k = tid; k < KC; k += 256) {
        int c = counts[k];
        if (c > 0) {
            float p = (float)c / 32768.0f;
            ep += p * logf(p);
        }
    }
    red[tid] = ep; __syncthreads();
    for (int s = 128; s > 0; s >>= 1) {
        if (tid < s) red[tid] += red[tid + s];
        __syncthreads();
    }
    if (tid == 0) {
        out_sc[0] = loss;
        out_sc[1] = loss;
        out_sc[2] = -red[0] * 1.4426950408889634f;
    }
}

// ---------------------------------------------------------------------------
extern "C" void kernel_launch(void* const* d_in, const int* in_sizes, int n_in,
                              void* d_out, int out_size, void* d_ws, size_t ws_size,
                              hipStream_t stream) {
    (void)in_sizes; (void)n_in; (void)out_size; (void)ws_size;
    const float* input  = (const float*)d_in[0];
    const float* W_send = (const float*)d_in[1];
    const float* b_send = (const float*)d_in[2];
    const float* emb    = (const float*)d_in[3];
    const float* W_recv = (const float*)d_in[4];
    const float* b_recv = (const float*)d_in[5];
    float* out = (float*)d_out;

    char* ws = (char*)d_ws;
    _Float16* Ze  = (_Float16*)(ws);                  //  8 MB  [32768][128]
    float*    D   = (float*)(ws + 8388608);           // 16 MB
    _Float16* Ee  = (_Float16*)(ws + 25165824);       //  1 MB  [4096][128]
    float*    sqr = (float*)(ws + 26214400);          // 16 KB
    int*      idx = (int*)  (ws + 26230784);          // 128 KB
    int*   counts = (int*)  (ws + 26361856);          // 16 KB
    float* lpart  = (float*)(ws + 26378240);          //  2 KB (512 floats)
    _Float16* Wh  = (_Float16*)(ws + 26380288);       // 128 KB [64][1024]
    _Float16* Wl  = (_Float16*)(ws + 26511360);       // 128 KB [64][1024]

    float* out_x   = out;                    // 33554432
    float* out_idx = out + 33554432;         // 32768
    float* out_sc  = out + 33587200;         // 3

    k_prep<<<1552, 256, 0, stream>>>(emb, W_send, W_recv, b_recv,
                                     Ee, sqr, Wh, Wl, D, counts);
    k_send<<<512, 256, 0, stream>>>(input, Wh, Wl, b_send, Ze);
    k_score<<<512, 512, 0, stream>>>(Ee, Ze, sqr, idx, out_idx, counts, lpart);
    k_gather<<<2048, 256, 0, stream>>>(D, idx, out_x);
    k_final<<<1, 256, 0, stream>>>(counts, lpart, out_sc);
}

// Round 10
// 86.822 us; speedup vs baseline: 1.8084x; 1.3931x over previous
//
#include <hip/hip_runtime.h>

#define DIN 1024
#define DC 64
#define KC 4096

typedef _Float16 f16x8 __attribute__((ext_vector_type(8)));
typedef _Float16 f16x4 __attribute__((ext_vector_type(4)));
typedef float f32x4 __attribute__((ext_vector_type(4)));

__device__ __forceinline__ void gll16(const void* g, void* l) {
    __builtin_amdgcn_global_load_lds(
        (const __attribute__((address_space(1))) unsigned int*)g,
        (__attribute__((address_space(3))) unsigned int*)l, 16, 0, 0);
}

// ---------------------------------------------------------------------------
// Merged prep + dec.
//   b <  1024 : Ee [4096][64] f16 (eh), sqr fp32 (exact), zero counts
//   b <  1040 : W_send -> Wh [64][1024] f16 (transposed)
//   b >= 1040 : D = emb @ W_recv + b_recv  (512 blocks)
__global__ __launch_bounds__(256) void k_prep(const float* __restrict__ emb,
                                              const float* __restrict__ Ws,
                                              const float* __restrict__ Wr,
                                              const float* __restrict__ br,
                                              _Float16* __restrict__ Ee,
                                              float* __restrict__ sqr,
                                              _Float16* __restrict__ Wh,
                                              float* __restrict__ D,
                                              int* __restrict__ counts) {
    int b = blockIdx.x;
    int tid = threadIdx.x;
    if (b < 1024) {
        int code = b * 4 + (tid >> 6);
        int lane = tid & 63;
        float v = emb[(size_t)code * DC + lane];
        Ee[(size_t)code * 64 + lane] = (_Float16)v;
        float s = v * v;
        #pragma unroll
        for (int m = 1; m < 64; m <<= 1) s += __shfl_xor(s, m);
        if (lane == 0) sqr[code] = s;
        if (tid < 4) counts[b * 4 + tid] = 0;
        return;
    }
    if (b < 1040) {
        int k0 = (b - 1024) * 64;
        #pragma unroll
        for (int it = 0; it < 16; ++it) {
            int q = it * 256 + tid;          // 4096 = 64c x 64k
            int c = q >> 6, kl = q & 63;
            float v = Ws[(size_t)(k0 + kl) * 64 + c];
            Wh[(size_t)c * 1024 + k0 + kl] = (_Float16)v;
        }
        return;
    }
    // ---- decoder codebook: D = emb @ W_recv + b_recv ----
    __shared__ float Ek[64][68];    // [dim][code]
    __shared__ float Wt[64][132];   // [dim][col]
    int bb = b - 1040;
    int cb0  = (bb & 63) * 64;
    int col0 = (bb >> 6) * 128;
    int tx = tid & 15;
    int ty = tid >> 4;

    for (int q = tid; q < 1024; q += 256) {
        int r = q >> 4, c4 = q & 15;
        float4 v = *(const float4*)&emb[(size_t)(cb0 + r) * DC + c4*4];
        Ek[c4*4+0][r] = v.x; Ek[c4*4+1][r] = v.y;
        Ek[c4*4+2][r] = v.z; Ek[c4*4+3][r] = v.w;
    }
    for (int q = tid; q < 2048; q += 256) {
        int c = q >> 5, k4 = q & 31;
        *(float4*)&Wt[c][k4*4] = *(const float4*)&Wr[(size_t)c * DIN + col0 + k4*4];
    }
    __syncthreads();

    float acc[4][8] = {};
    #pragma unroll 8
    for (int c = 0; c < 64; ++c) {
        float4 av = *(const float4*)&Ek[c][tx*4];
        float4 w0 = *(const float4*)&Wt[c][ty*8];
        float4 w1 = *(const float4*)&Wt[c][ty*8 + 4];
        float a[4] = {av.x, av.y, av.z, av.w};
        float w[8] = {w0.x, w0.y, w0.z, w0.w, w1.x, w1.y, w1.z, w1.w};
        #pragma unroll
        for (int i = 0; i < 4; ++i)
            #pragma unroll
            for (int j = 0; j < 8; ++j)
                acc[i][j] += a[i] * w[j];
    }

    #pragma unroll
    for (int i = 0; i < 4; ++i) {
        int code = cb0 + tx*4 + i;
        float4 o0, o1;
        o0.x = acc[i][0] + br[col0 + ty*8 + 0];
        o0.y = acc[i][1] + br[col0 + ty*8 + 1];
        o0.z = acc[i][2] + br[col0 + ty*8 + 2];
        o0.w = acc[i][3] + br[col0 + ty*8 + 3];
        o1.x = acc[i][4] + br[col0 + ty*8 + 4];
        o1.y = acc[i][5] + br[col0 + ty*8 + 5];
        o1.z = acc[i][6] + br[col0 + ty*8 + 6];
        o1.w = acc[i][7] + br[col0 + ty*8 + 7];
        *(float4*)&D[(size_t)code * DIN + col0 + ty*8]     = o0;
        *(float4*)&D[(size_t)code * DIN + col0 + ty*8 + 4] = o1;
    }
}

// ---------------------------------------------------------------------------
// z = input @ W_send + b_send, single-pass f16 MFMA; emits Ze [32768][64] f16.
// HBM-read-bound (134 MB input); LDS 32 KB dbuf -> high occupancy.
__global__ __launch_bounds__(256) void k_send(const float* __restrict__ in,
                                              const _Float16* __restrict__ Wh,
                                              const float* __restrict__ bs,
                                              _Float16* __restrict__ Ze) {
    __shared__ char smem[32768];
    const int tid = threadIdx.x;
    const int row0 = blockIdx.x * 64;
    const int wid = tid >> 6, lane = tid & 63;
    const int c15 = lane & 15, g = lane >> 4;
    const int wm = wid >> 1, wn = wid & 1;

    f32x4 acc[2][2];
    const f32x4 z4 = {0.f, 0.f, 0.f, 0.f};
    #pragma unroll
    for (int mf = 0; mf < 2; ++mf)
        #pragma unroll
        for (int nf = 0; nf < 2; ++nf) acc[mf][nf] = z4;

    int abyte[2], aswz[2], bbyte[2], bswz[2];
    #pragma unroll
    for (int mf = 0; mf < 2; ++mf) {
        int r = wm * 32 + mf * 16 + c15;
        abyte[mf] = r * 128; aswz[mf] = (r & 7) << 4;
    }
    #pragma unroll
    for (int nf = 0; nf < 2; ++nf) {
        int c = wn * 32 + nf * 16 + c15;
        bbyte[nf] = c * 128; bswz[nf] = (c & 7) << 4;
    }
    const int g16 = g * 16;

    auto stageB = [&](int buf, int s) {      // Wh k-chunk: 64 rows x 128 B
        char* dst = smem + buf * 16384 + 8192;
        #pragma unroll
        for (int r = 0; r < 2; ++r) {
            int p = r * 4096 + wid * 1024 + lane * 16;
            int row = p >> 7, off = p & 127;
            int soff = off ^ ((row & 7) << 4);
            gll16((const char*)Wh + (size_t)row * 2048 + s * 128 + soff,
                  dst + p);
        }
    };

    auto loadA = [&](int s, float4* a) {
        #pragma unroll
        for (int it = 0; it < 4; ++it) {
            int q = it * 256 + tid;
            int r = q >> 4, c4 = q & 15;
            a[it] = *(const float4*)&in[(size_t)(row0 + r) * DIN + s * 64 + c4 * 4];
        }
    };

    auto writeA = [&](int buf, const float4* a) {
        char* Ah = smem + buf * 16384;
        #pragma unroll
        for (int it = 0; it < 4; ++it) {
            int q = it * 256 + tid;
            int r = q >> 4, c4 = q & 15;
            float v[4] = {a[it].x, a[it].y, a[it].z, a[it].w};
            f16x4 h;
            #pragma unroll
            for (int j = 0; j < 4; ++j) h[j] = (_Float16)v[j];
            int o = r * 128 + ((c4 * 8) ^ ((r & 7) << 4));
            *(f16x4*)(Ah + o) = h;
        }
    };

    auto compute = [&](int buf) {
        const char* Ah = smem + buf * 16384;
        const char* Bh = Ah + 8192;
        #pragma unroll
        for (int ks = 0; ks < 2; ++ks) {
            int koff = ks * 64 + g16;
            f16x8 bh[2];
            #pragma unroll
            for (int nf = 0; nf < 2; ++nf)
                bh[nf] = *(const f16x8*)(Bh + bbyte[nf] + (koff ^ bswz[nf]));
            #pragma unroll
            for (int mf = 0; mf < 2; ++mf) {
                f16x8 ah = *(const f16x8*)(Ah + abyte[mf] + (koff ^ aswz[mf]));
                #pragma unroll
                for (int nf = 0; nf < 2; ++nf)
                    acc[mf][nf] = __builtin_amdgcn_mfma_f32_16x16x32_f16(
                        ah, bh[nf], acc[mf][nf], 0, 0, 0);
            }
        }
    };

    {
        float4 a0[4];
        loadA(0, a0);
        stageB(0, 0);
        writeA(0, a0);
    }
    __syncthreads();

    for (int s = 0; s < 16; ++s) {
        int c = s & 1;
        float4 an[4];
        if (s < 15) {
            loadA(s + 1, an);
            stageB(c ^ 1, s + 1);
        }
        compute(c);
        if (s < 15) writeA(c ^ 1, an);
        __syncthreads();
    }

    // epilogue: z = acc + bias -> f16 -> Ze
    #pragma unroll
    for (int nf = 0; nf < 2; ++nf) {
        int col = wn * 32 + nf * 16 + c15;
        float bias = bs[col];
        #pragma unroll
        for (int mf = 0; mf < 2; ++mf) {
            #pragma unroll
            for (int r2 = 0; r2 < 4; ++r2) {
                float zv = acc[mf][nf][r2] + bias;
                int row = row0 + wm * 32 + mf * 16 + g * 4 + r2;
                Ze[(size_t)row * 64 + col] = (_Float16)zv;
            }
        }
    }
}

// ---------------------------------------------------------------------------
// Persistent-Z score kernel, single-pass f16 + fused loss.
// Grid 512 x 512 thr; block = 64 rows; E double-buffered (2x16KB).
__global__ __launch_bounds__(512, 4) void k_score(const _Float16* __restrict__ Ee,
                                                  const _Float16* __restrict__ Ze,
                                                  const float* __restrict__ sqr,
                                                  int* __restrict__ idx,
                                                  float* __restrict__ out_idx,
                                                  int* __restrict__ counts,
                                                  float* __restrict__ lpart) {
    __shared__ char smem[35072];          // 2x16KB E dbuf + 2.25KB reduce
    const int tid = threadIdx.x;
    const int row0 = blockIdx.x * 64;
    const int wid = tid >> 6, lane = tid & 63;
    const int c15 = lane & 15, g = lane >> 4;
    const int wm = wid >> 1;              // 0..3 : codes wm*32..+31
    const int wn = wid & 1;               // 0..1 : rows  wn*32..+31
    const int g16 = g * 16;

    // ---- Z fragments: load once into registers (zh only) ----
    f16x8 zfh[2][2];                      // [kstep j][nf]
    #pragma unroll
    for (int nf = 0; nf < 2; ++nf) {
        const _Float16* zr = Ze + (size_t)(row0 + wn * 32 + nf * 16 + c15) * 64;
        #pragma unroll
        for (int j = 0; j < 2; ++j)
            zfh[j][nf] = *(const f16x8*)(zr + j * 32 + g * 8);
    }

    int rbase[2], rx[2];
    #pragma unroll
    for (int mf = 0; mf < 2; ++mf) {
        int r = wm * 32 + mf * 16 + c15;
        rbase[mf] = r * 128;
        rx[mf] = (r & 7) << 4;
    }

    auto stage = [&](int ch, int buf) {   // 128 codes x 128 B = 16 KB
        char* dst = smem + buf * 16384;
        const char* src = (const char*)Ee + (size_t)ch * 16384;
        #pragma unroll
        for (int t = 0; t < 2; ++t) {
            int p = t * 8192 + tid * 16;
            int r = p >> 7, b = p & 127;
            gll16(src + r * 128 + (b ^ ((r & 7) << 4)), dst + p);
        }
    };

    float bv[2];
    int   bi[2];
    #pragma unroll
    for (int nf = 0; nf < 2; ++nf) { bv[nf] = 3.402823466e38f; bi[nf] = 0; }

    const f32x4 zz4 = {0.f, 0.f, 0.f, 0.f};

    stage(0, 0);
    __syncthreads();

    for (int ch = 0; ch < 32; ++ch) {
        const int buf = ch & 1;
        f32x4 sqv[2];
        #pragma unroll
        for (int mf = 0; mf < 2; ++mf)
            sqv[mf] = *(const f32x4*)(sqr + ch * 128 + wm * 32 + mf * 16 + g * 4);

        if (ch < 31) stage(ch + 1, buf ^ 1);

        const char* base = smem + buf * 16384;
        f32x4 acc[2][2];
        #pragma unroll
        for (int j = 0; j < 2; ++j) {
            const int kbyte = j * 64 + g16;
            f16x8 af[2];
            #pragma unroll
            for (int mf = 0; mf < 2; ++mf)
                af[mf] = *(const f16x8*)(base + rbase[mf] + (kbyte ^ rx[mf]));
            #pragma unroll
            for (int mf = 0; mf < 2; ++mf)
                #pragma unroll
                for (int nf = 0; nf < 2; ++nf)
                    acc[mf][nf] = __builtin_amdgcn_mfma_f32_16x16x32_f16(
                        af[mf], zfh[j][nf],
                        j == 0 ? zz4 : acc[mf][nf], 0, 0, 0);
        }

        #pragma unroll
        for (int nf = 0; nf < 2; ++nf) {
            #pragma unroll
            for (int mf = 0; mf < 2; ++mf) {
                f32x4 v = sqv[mf] - acc[mf][nf] * 2.0f;
                #pragma unroll
                for (int r2 = 0; r2 < 4; ++r2) {
                    if (v[r2] < bv[nf]) {
                        bv[nf] = v[r2];
                        bi[nf] = ch * 128 + wm * 32 + mf * 16 + g * 4 + r2;
                    }
                }
            }
        }
        __syncthreads();
    }

    // ---- final reduction: argmin + ||z||^2 + loss partial ----
    float* redv = (float*)(smem + 32768);          // [4][64]
    int*   redi = (int*)(smem + 33792);            // [4][64]
    float* zsqa = (float*)(smem + 34816);          // [64]

    #pragma unroll
    for (int nf = 0; nf < 2; ++nf) {
        float v_ = bv[nf]; int i_ = bi[nf];
        #pragma unroll
        for (int m = 16; m <= 32; m <<= 1) {
            float ov = __shfl_xor(v_, m);
            int oi = __shfl_xor(i_, m);
            if (ov < v_ || (ov == v_ && oi < i_)) { v_ = ov; i_ = oi; }
        }
        if (g == 0) {
            int rl = wn * 32 + nf * 16 + c15;
            redv[wm * 64 + rl] = v_;
            redi[wm * 64 + rl] = i_;
        }
    }
    // ||z~||^2 per row (z~ = zh, consistent with the scored z)
    if (wm == 0) {
        #pragma unroll
        for (int nf = 0; nf < 2; ++nf) {
            float s = 0.f;
            #pragma unroll
            for (int j = 0; j < 2; ++j)
                #pragma unroll
                for (int e = 0; e < 8; ++e) {
                    float zv = (float)zfh[j][nf][e];
                    s += zv * zv;
                }
            s += __shfl_xor(s, 16);
            s += __shfl_xor(s, 32);
            if (g == 0) zsqa[wn * 32 + nf * 16 + c15] = s;
        }
    }
    __syncthreads();
    if (tid < 64) {
        float v0 = redv[tid]; int i0 = redi[tid];
        #pragma unroll
        for (int w = 1; w < 4; ++w) {
            float v1 = redv[w * 64 + tid]; int i1 = redi[w * 64 + tid];
            if (v1 < v0 || (v1 == v0 && i1 < i0)) { v0 = v1; i0 = i1; }
        }
        int grow = row0 + tid;
        idx[grow] = i0;
        out_idx[grow] = (float)i0;
        atomicAdd(&counts[i0], 1);
        float lossv = v0 + zsqa[tid];
        #pragma unroll
        for (int m = 1; m < 64; m <<= 1) lossv += __shfl_xor(lossv, m);
        if (tid == 0) lpart[blockIdx.x] = lossv;
    }
}

// ---------------------------------------------------------------------------
// x[s] = D[idx[s]] (blocks 0..2047); block 2048 computes the output scalars.
__global__ __launch_bounds__(256) void k_gather(const float* __restrict__ D,
                                                const int* __restrict__ idx,
                                                const int* __restrict__ counts,
                                                const float* __restrict__ lpart,
                                                float* __restrict__ x,
                                                float* __restrict__ out_sc) {
    int tid = threadIdx.x;
    if (blockIdx.x == 2048) {
        __shared__ float red[256];
        red[tid] = lpart[tid] + lpart[256 + tid];
        __syncthreads();
        for (int s = 128; s > 0; s >>= 1) {
            if (tid < s) red[tid] += red[tid + s];
            __syncthreads();
        }
        float loss = red[0];
        __syncthreads();
        float ep = 0.f;
        for (int k = tid; k < KC; k += 256) {
            int c = counts[k];
            if (c > 0) {
                float p = (float)c / 32768.0f;
                ep += p * logf(p);
            }
        }
        red[tid] = ep; __syncthreads();
        for (int s = 128; s > 0; s >>= 1) {
            if (tid < s) red[tid] += red[tid + s];
            __syncthreads();
        }
        if (tid == 0) {
            out_sc[0] = loss;
            out_sc[1] = loss;
            out_sc[2] = -red[0] * 1.4426950408889634f;
        }
        return;
    }
    int gidx = blockIdx.x * 256 + tid;
    #pragma unroll
    for (int it = 0; it < 4; ++it) {
        int f = gidx + it * 524288;
        int row = f >> 6, c = f & 63;
        int code = idx[row];
        *(float4*)&x[(size_t)row * DIN + c*4] =
            *(const float4*)&D[(size_t)code * DIN + c*4];
    }
}

// ---------------------------------------------------------------------------
extern "C" void kernel_launch(void* const* d_in, const int* in_sizes, int n_in,
                              void* d_out, int out_size, void* d_ws, size_t ws_size,
                              hipStream_t stream) {
    (void)in_sizes; (void)n_in; (void)out_size; (void)ws_size;
    const float* input  = (const float*)d_in[0];
    const float* W_send = (const float*)d_in[1];
    const float* b_send = (const float*)d_in[2];
    const float* emb    = (const float*)d_in[3];
    const float* W_recv = (const float*)d_in[4];
    const float* b_recv = (const float*)d_in[5];
    float* out = (float*)d_out;

    char* ws = (char*)d_ws;
    _Float16* Ze  = (_Float16*)(ws);                  //  4 MB  [32768][64]
    float*    D   = (float*)(ws + 4194304);           // 16 MB
    _Float16* Ee  = (_Float16*)(ws + 20971520);       // 512 KB [4096][64]
    float*    sqr = (float*)(ws + 21495808);          // 16 KB
    int*      idx = (int*)  (ws + 21512192);          // 128 KB
    int*   counts = (int*)  (ws + 21643264);          // 16 KB
    float* lpart  = (float*)(ws + 21659648);          //  2 KB (512 floats)
    _Float16* Wh  = (_Float16*)(ws + 21661696);       // 128 KB [64][1024]

    float* out_x   = out;                    // 33554432
    float* out_idx = out + 33554432;         // 32768
    float* out_sc  = out + 33587200;         // 3

    k_prep<<<1552, 256, 0, stream>>>(emb, W_send, W_recv, b_recv,
                                     Ee, sqr, Wh, D, counts);
    k_send<<<512, 256, 0, stream>>>(input, Wh, b_send, Ze);
    k_score<<<512, 512, 0, stream>>>(Ee, Ze, sqr, idx, out_idx, counts, lpart);
    k_gather<<<2049, 256, 0, stream>>>(D, idx, counts, lpart, out_x, out_sc);
}